// Round 5
// baseline (410.277 us; speedup 1.0000x reference)
//
#include <hip/hip_runtime.h>
#include <hip/hip_bf16.h>

#define BB 16
#define NI 2048
#define NA 2048
#define DD 256
#define KVB 64
#define NT2 (NA / KVB)   // 32

typedef _Float16 half8 __attribute__((ext_vector_type(8)));
typedef __attribute__((ext_vector_type(4))) float f32x4;

static __device__ __forceinline__ unsigned short f2h(float f) {
  union { _Float16 h; unsigned short u; } x; x.h = (_Float16)f; return x.u;
}
static __device__ __forceinline__ float h2f(unsigned short u) {
  union { _Float16 h; unsigned short u; } x; x.u = u; return (float)x.h;
}

// ---------------- prep: attendee -> ksw (fp16, row-XOR-swizzled) + vt (fp16, transposed) ----
__global__ void prep_kernel(const float* __restrict__ a,
                            unsigned short* __restrict__ ksw,
                            unsigned short* __restrict__ vt) {
  __shared__ float t[64][65];
  int bx = blockIdx.x;
  int b = bx >> 7;
  int r = bx & 127;
  int jt = r >> 2, dt = r & 3;
  int j0 = jt * 64, d0 = dt * 64;
  int tid = threadIdx.x;
  int rr = tid >> 4, c4 = tid & 15;
#pragma unroll
  for (int k = 0; k < 4; ++k) {
    int row = rr + k * 16;
    int j = j0 + row;
    float4 v = *(const float4*)(a + ((size_t)b * NA + j) * DD + d0 + c4 * 4);
    ushort4 hh;
    hh.x = f2h(v.x); hh.y = f2h(v.y); hh.z = f2h(v.z); hh.w = f2h(v.w);
    int dd = d0 + c4 * 4;
    int u = dd >> 3, sub = dd & 7;            // sub in {0,4}
    int us = u ^ (j & 7);
    *(ushort4*)(ksw + ((size_t)b * NA + j) * DD + us * 8 + sub) = hh;
    t[row][c4 * 4 + 0] = v.x; t[row][c4 * 4 + 1] = v.y;
    t[row][c4 * 4 + 2] = v.z; t[row][c4 * 4 + 3] = v.w;
  }
  __syncthreads();
#pragma unroll
  for (int k = 0; k < 4; ++k) {
    int d = rr + k * 16;
    ushort4 o;
    o.x = f2h(t[c4 * 4 + 0][d]); o.y = f2h(t[c4 * 4 + 1][d]);
    o.z = f2h(t[c4 * 4 + 2][d]); o.w = f2h(t[c4 * 4 + 3][d]);
    *(ushort4*)(vt + ((size_t)b * DD + d0 + d) * NA + j0 + c4 * 4) = o;
  }
}

// ---------------- tw: W -> W^T hi/lo fp16, row-XOR-swizzled [e][d] ----------------
__global__ void tw_kernel(const float* __restrict__ w,
                          unsigned short* __restrict__ wth,
                          unsigned short* __restrict__ wtl) {
  __shared__ float t[64][65];
  int bx = blockIdx.x;
  int dt = bx >> 2, et = bx & 3;
  int d0 = dt * 64, e0 = et * 64;
  int tid = threadIdx.x;
  int rr = tid >> 4, c4 = (tid & 15) * 4;
#pragma unroll
  for (int k = 0; k < 4; ++k) {
    int row = rr + k * 16;   // d index
    float4 v = *(const float4*)(w + (size_t)(d0 + row) * DD + e0 + c4);
    t[row][c4 + 0] = v.x; t[row][c4 + 1] = v.y; t[row][c4 + 2] = v.z; t[row][c4 + 3] = v.w;
  }
  __syncthreads();
#pragma unroll
  for (int k = 0; k < 4; ++k) {
    int e = rr + k * 16;
    int eg = e0 + e;
    ushort4 h, l;
    float v0 = t[c4 + 0][e]; h.x = f2h(v0); l.x = f2h(v0 - h2f(h.x));
    float v1 = t[c4 + 1][e]; h.y = f2h(v1); l.y = f2h(v1 - h2f(h.y));
    float v2 = t[c4 + 2][e]; h.z = f2h(v2); l.z = f2h(v2 - h2f(h.z));
    float v3 = t[c4 + 3][e]; h.w = f2h(v3); l.w = f2h(v3 - h2f(h.w));
    int dd = d0 + c4;
    int u = dd >> 3, sub = dd & 7;
    size_t off = (size_t)eg * DD + ((u ^ (eg & 7)) * 8) + sub;
    *(ushort4*)(wth + off) = h;
    *(ushort4*)(wtl + off) = l;
  }
}

// ---------------- Q = x @ W  (2-term fp16 MFMA), writes qf fp16 row-major ----------------
__global__ __launch_bounds__(256, 2) void qgemm_kernel(
    const float* __restrict__ x, const unsigned short* __restrict__ wth,
    const unsigned short* __restrict__ wtl, unsigned short* __restrict__ qf) {
  __shared__ unsigned short wb[2][64 * 256];   // 64 KB
  const int tid = threadIdx.x;
  const int lane = tid & 63;
  const int wv = tid >> 6;
  const int quad = lane >> 4;
  const int l16 = lane & 15;
  const int m0 = blockIdx.x * 64;

  half8 xf[8];
  {
    const float* xr = x + (size_t)(m0 + wv * 16 + l16) * DD;
#pragma unroll
    for (int c = 0; c < 8; ++c) {
      float4 a = *(const float4*)(xr + c * 32 + quad * 8);
      float4 b = *(const float4*)(xr + c * 32 + quad * 8 + 4);
      half8 v;
      v[0] = (_Float16)a.x; v[1] = (_Float16)a.y; v[2] = (_Float16)a.z; v[3] = (_Float16)a.w;
      v[4] = (_Float16)b.x; v[5] = (_Float16)b.y; v[6] = (_Float16)b.z; v[7] = (_Float16)b.w;
      xf[c] = v;
    }
  }

#pragma unroll 1
  for (int eg = 0; eg < 4; ++eg) {
    uint4 t0[8], t1[8];
    {
      const unsigned short* sh = wth + (size_t)(eg * 64) * DD;
      const unsigned short* sl = wtl + (size_t)(eg * 64) * DD;
#pragma unroll
      for (int i = 0; i < 8; ++i) {
        t0[i] = *(const uint4*)(sh + (i * 256 + tid) * 8);
        t1[i] = *(const uint4*)(sl + (i * 256 + tid) * 8);
      }
    }
    __syncthreads();
#pragma unroll
    for (int i = 0; i < 8; ++i) {
      *(uint4*)(wb[0] + (i * 256 + tid) * 8) = t0[i];
      *(uint4*)(wb[1] + (i * 256 + tid) * 8) = t1[i];
    }
    __syncthreads();
#pragma unroll
    for (int etl = 0; etl < 4; ++etl) {
      int rloc = etl * 16 + l16;
      f32x4 acc; acc[0] = acc[1] = acc[2] = acc[3] = 0.f;
#pragma unroll
      for (int c = 0; c < 8; ++c) {
        int off = rloc * DD + (((4 * c + quad) ^ (rloc & 7)) * 8);
        half8 wh = *(const half8*)(wb[0] + off);
        half8 wl = *(const half8*)(wb[1] + off);
        acc = __builtin_amdgcn_mfma_f32_16x16x32_f16(xf[c], wh, acc, 0, 0, 0);
        acc = __builtin_amdgcn_mfma_f32_16x16x32_f16(xf[c], wl, acc, 0, 0, 0);
      }
      int e = eg * 64 + etl * 16 + l16;
#pragma unroll
      for (int rg = 0; rg < 4; ++rg) {
        qf[(size_t)(m0 + wv * 16 + 4 * quad + rg) * DD + e] = f2h(acc[rg]);
      }
    }
  }
}

// ---------------- flash attention v5: KVB=64, independent pairs ----------------
// 4 waves = 2 pairs; pair owns 32 q; both waves compute QK^T (duplicated), PV splits d.
// Softmax per-wave; per-lane partial denominators (epilogue reduce). K single-buffer
// 32 KB: reg-prefetch at top, ds_write after b1; V in two 8-load batches.
__global__ __launch_bounds__(256, 2) void attn_kernel(
    const unsigned short* __restrict__ ksw, const unsigned short* __restrict__ vt,
    const unsigned short* __restrict__ qf, float* __restrict__ out) {
  __shared__ unsigned short kls[KVB * DD];      // 32 KB
  __shared__ unsigned short pls[4][32 * 72];    // 18.4 KB (pad 72)

  const int tid = threadIdx.x;
  const int lane = tid & 63;
  const int wv = tid >> 6;       // 0..3
  const int p = wv >> 1;         // pair
  const int h = wv & 1;          // d-half
  const int quad = lane >> 4;
  const int l16 = lane & 15;

  int bx = blockIdx.x;
  int lbx = (bx & 7) * 64 + (bx >> 3);   // XCD-chunked (512 = 8*64)
  const int b = lbx >> 5;
  const int qbase = (lbx & 31) * 64 + p * 32;

  const size_t abase = (size_t)b * NA * DD;
  const size_t vbase = (size_t)b * (size_t)DD * NA;

  // Q fragments (both q-tiles of the pair)
  half8 qh[2][8];
#pragma unroll
  for (int qt = 0; qt < 2; ++qt) {
    const size_t qrow = ((size_t)b * NI + qbase + qt * 16 + l16) * DD;
#pragma unroll
    for (int c = 0; c < 8; ++c)
      qh[qt][c] = *(const half8*)(qf + qrow + c * 32 + quad * 8);
  }

  f32x4 acc[2][8];
#pragma unroll
  for (int qt = 0; qt < 2; ++qt)
#pragma unroll
    for (int dt = 0; dt < 8; ++dt) { acc[qt][dt][0] = 0.f; acc[qt][dt][1] = 0.f; acc[qt][dt][2] = 0.f; acc[qt][dt][3] = 0.f; }
  float m0r = -INFINITY, m1r = -INFINITY;
  float l0 = 0.f, l1 = 0.f;    // per-lane partial denominators

  // prologue: stage K tile 0 (8 x uint4 per thread, 16B-interleaved)
  {
    const unsigned short* s = ksw + abase;
#pragma unroll
    for (int i = 0; i < 8; ++i)
      *(uint4*)(kls + (i * 256 + tid) * 8) = *(const uint4*)(s + (i * 256 + tid) * 8);
  }
  __syncthreads();

  unsigned short* pw = pls[wv];

#pragma unroll 1
  for (int kt = 0; kt < NT2; ++kt) {
    const int jb = kt * KVB;

    // ---- V batch 0 (jsub=0) from L2, consumed in PV at end ----
    half8 vb0[8];
#pragma unroll
    for (int dt = 0; dt < 8; ++dt)
      vb0[dt] = *(const half8*)(vt + vbase + (size_t)(h * 128 + dt * 16 + l16) * NA + jb + quad * 8);

    // ---- K(kt+1) prefetch into regs ----
    uint4 kf[8];
    if (kt + 1 < NT2) {
      const unsigned short* s = ksw + abase + (size_t)(jb + KVB) * DD;
#pragma unroll
      for (int i = 0; i < 8; ++i)
        kf[i] = *(const uint4*)(s + (i * 256 + tid) * 8);
    }

    // ---- QK^T: S^T[64 j x 32 q] ----
    f32x4 st[2][4];
#pragma unroll
    for (int a = 0; a < 2; ++a)
#pragma unroll
      for (int jt = 0; jt < 4; ++jt) { st[a][jt][0] = 0.f; st[a][jt][1] = 0.f; st[a][jt][2] = 0.f; st[a][jt][3] = 0.f; }
#pragma unroll
    for (int c = 0; c < 8; ++c) {
#pragma unroll
      for (int jt = 0; jt < 4; ++jt) {
        int jr = jt * 16 + l16;
        half8 kfr = *(const half8*)(kls + jr * DD + (((4 * c + quad) ^ (jr & 7)) * 8));
        st[0][jt] = __builtin_amdgcn_mfma_f32_16x16x32_f16(kfr, qh[0][c], st[0][jt], 0, 0, 0);
        st[1][jt] = __builtin_amdgcn_mfma_f32_16x16x32_f16(kfr, qh[1][c], st[1][jt], 0, 0, 0);
      }
    }
    __syncthreads();   // b1: all K reads done

    // ---- stage next K (writes after b1; visible after b2) ----
    if (kt + 1 < NT2) {
#pragma unroll
      for (int i = 0; i < 8; ++i)
        *(uint4*)(kls + (i * 256 + tid) * 8) = kf[i];
    }

    // ---- V batch 1 (jsub=1), covered by softmax below ----
    half8 vb1[8];
#pragma unroll
    for (int dt = 0; dt < 8; ++dt)
      vb1[dt] = *(const half8*)(vt + vbase + (size_t)(h * 128 + dt * 16 + l16) * NA + jb + 32 + quad * 8);

    // ---- per-wave softmax max ----
    float mt0 = fmaxf(fmaxf(fmaxf(st[0][0][0], st[0][0][1]), fmaxf(st[0][0][2], st[0][0][3])),
                      fmaxf(fmaxf(st[0][1][0], st[0][1][1]), fmaxf(st[0][1][2], st[0][1][3])));
    mt0 = fmaxf(mt0, fmaxf(fmaxf(fmaxf(st[0][2][0], st[0][2][1]), fmaxf(st[0][2][2], st[0][2][3])),
                           fmaxf(fmaxf(st[0][3][0], st[0][3][1]), fmaxf(st[0][3][2], st[0][3][3]))));
    float mt1 = fmaxf(fmaxf(fmaxf(st[1][0][0], st[1][0][1]), fmaxf(st[1][0][2], st[1][0][3])),
                      fmaxf(fmaxf(st[1][1][0], st[1][1][1]), fmaxf(st[1][1][2], st[1][1][3])));
    mt1 = fmaxf(mt1, fmaxf(fmaxf(fmaxf(st[1][2][0], st[1][2][1]), fmaxf(st[1][2][2], st[1][2][3])),
                           fmaxf(fmaxf(st[1][3][0], st[1][3][1]), fmaxf(st[1][3][2], st[1][3][3]))));
    mt0 = fmaxf(mt0, __shfl_xor(mt0, 16)); mt0 = fmaxf(mt0, __shfl_xor(mt0, 32));
    mt1 = fmaxf(mt1, __shfl_xor(mt1, 16)); mt1 = fmaxf(mt1, __shfl_xor(mt1, 32));
    bool upd = __any((mt0 > m0r + 8.f) || (mt1 > m1r + 8.f)) != 0;
    if (upd) {
      float mn0 = fmaxf(m0r, mt0), mn1 = fmaxf(m1r, mt1);
      float sc0 = __expf(m0r - mn0), sc1 = __expf(m1r - mn1);
      l0 *= sc0; l1 *= sc1;
#pragma unroll
      for (int rg = 0; rg < 4; ++rg) {
        float a0 = __shfl(sc0, 4 * quad + rg);
        float a1 = __shfl(sc1, 4 * quad + rg);
#pragma unroll
        for (int dt = 0; dt < 8; ++dt) { acc[0][dt][rg] *= a0; acc[1][dt][rg] *= a1; }
      }
      m0r = mn0; m1r = mn1;
    }

    // ---- exp + pack + per-lane partial sums + P writes ----
    float s0 = 0.f, s1 = 0.f;
#pragma unroll
    for (int jt = 0; jt < 4; ++jt) {
      float e0 = __expf(st[0][jt][0] - m0r), e1 = __expf(st[0][jt][1] - m0r);
      float e2 = __expf(st[0][jt][2] - m0r), e3 = __expf(st[0][jt][3] - m0r);
      s0 += (e0 + e1) + (e2 + e3);
      ushort4 pk;
      pk.x = f2h(e0); pk.y = f2h(e1); pk.z = f2h(e2); pk.w = f2h(e3);
      *(ushort4*)(pw + l16 * 72 + jt * 16 + quad * 4) = pk;
      float f0 = __expf(st[1][jt][0] - m1r), f1 = __expf(st[1][jt][1] - m1r);
      float f2 = __expf(st[1][jt][2] - m1r), f3 = __expf(st[1][jt][3] - m1r);
      s1 += (f0 + f1) + (f2 + f3);
      pk.x = f2h(f0); pk.y = f2h(f1); pk.z = f2h(f2); pk.w = f2h(f3);
      *(ushort4*)(pw + (16 + l16) * 72 + jt * 16 + quad * 4) = pk;
    }
    l0 += s0; l1 += s1;   // per-lane partials; reduced in epilogue

    // ---- P reads (same-wave; lgkmcnt handled by compiler) ----
    half8 pa00 = *(const half8*)(pw + l16 * 72 + quad * 8);
    half8 pa01 = *(const half8*)(pw + l16 * 72 + 32 + quad * 8);
    half8 pa10 = *(const half8*)(pw + (16 + l16) * 72 + quad * 8);
    half8 pa11 = *(const half8*)(pw + (16 + l16) * 72 + 32 + quad * 8);

    // ---- PV (own d-half) ----
#pragma unroll
    for (int dt = 0; dt < 8; ++dt) {
      acc[0][dt] = __builtin_amdgcn_mfma_f32_16x16x32_f16(pa00, vb0[dt], acc[0][dt], 0, 0, 0);
      acc[1][dt] = __builtin_amdgcn_mfma_f32_16x16x32_f16(pa10, vb0[dt], acc[1][dt], 0, 0, 0);
    }
#pragma unroll
    for (int dt = 0; dt < 8; ++dt) {
      acc[0][dt] = __builtin_amdgcn_mfma_f32_16x16x32_f16(pa01, vb1[dt], acc[0][dt], 0, 0, 0);
      acc[1][dt] = __builtin_amdgcn_mfma_f32_16x16x32_f16(pa11, vb1[dt], acc[1][dt], 0, 0, 0);
    }
    __syncthreads();   // b2: new K visible for next kt
  }

  // ---- epilogue: reduce denominators, normalize, store ----
  l0 += __shfl_xor(l0, 16); l0 += __shfl_xor(l0, 32);
  l1 += __shfl_xor(l1, 16); l1 += __shfl_xor(l1, 32);
  float inv0 = 1.0f / l0, inv1 = 1.0f / l1;
  size_t ob = ((size_t)b * NI + qbase) * DD + h * 128;
#pragma unroll
  for (int rg = 0; rg < 4; ++rg) {
    float i0 = __shfl(inv0, 4 * quad + rg);
    float i1 = __shfl(inv1, 4 * quad + rg);
#pragma unroll
    for (int dt = 0; dt < 8; ++dt) {
      int d = dt * 16 + l16;
      out[ob + (size_t)(4 * quad + rg) * DD + d] = acc[0][dt][rg] * i0;
      out[ob + (size_t)(16 + 4 * quad + rg) * DD + d] = acc[1][dt][rg] * i1;
    }
  }
}

extern "C" void kernel_launch(void* const* d_in, const int* in_sizes, int n_in,
                              void* d_out, int out_size, void* d_ws, size_t ws_size,
                              hipStream_t stream) {
  const float* x = (const float*)d_in[0];        // [16,2048,256]
  const float* att = (const float*)d_in[1];      // [16,2048,256]
  const float* W = (const float*)d_in[2];        // [256,256]
  float* out = (float*)d_out;

  const size_t NE = (size_t)BB * NA * DD;        // 8388608
  unsigned short* w0  = (unsigned short*)d_ws;
  unsigned short* ksw = w0;
  unsigned short* vt  = w0 + NE;
  unsigned short* qf  = w0 + 2 * NE;
  unsigned short* wth = w0 + 3 * NE;
  unsigned short* wtl = w0 + 3 * NE + (size_t)DD * DD;

  prep_kernel<<<2048, 256, 0, stream>>>(att, ksw, vt);
  tw_kernel<<<16, 256, 0, stream>>>(W, wth, wtl);
  qgemm_kernel<<<512, 256, 0, stream>>>(x, wth, wtl, qf);
  attn_kernel<<<512, 256, 0, stream>>>(ksw, vt, qf, out);
}